// Round 1
// 9363.871 us; speedup vs baseline: 1.8942x; 1.8942x over previous
//
#include <hip/hip_runtime.h>

typedef __bf16 bf16_t;
typedef __bf16 bf16x8 __attribute__((ext_vector_type(8)));
typedef __bf16 bf16x4 __attribute__((ext_vector_type(4)));
typedef float  f32x4  __attribute__((ext_vector_type(4)));
typedef unsigned long long u64;

#define S_LEN 512
#define BATCH 64
#define HID 1024
#define BH (BATCH*HID)          /* 65536 */
#define G4 (4*HID)
#define NBLK 256                /* 128 layer-0 + 128 layer-1, 1 block/CU */
#define LBLK 128                /* blocks per layer */
#define NTHR 512                /* 8 waves: 4 M-tiles x 2 K-halves */
#define R0 8                    /* ring0 slots (L0->L1 skew budget) */
#define SKEW (R0-1)
#define FSTRIDE 32              /* counter spacing: 128 B */
#define NCNT 16                 /* sub-counters per layer */

__device__ __forceinline__ float sigmoid_f(float x) { return 1.f / (1.f + __expf(-x)); }
__device__ __forceinline__ float tanh_f(float x) {
    float e = __expf(-2.f * fabsf(x));
    float t = (1.f - e) / (1.f + e);
    return x >= 0.f ? t : -t;
}

__device__ __forceinline__ bf16x8 cvt8(const float* p) {
    float4 a = *reinterpret_cast<const float4*>(p);
    float4 b = *reinterpret_cast<const float4*>(p + 4);
    bf16x8 r;
    r[0] = (bf16_t)a.x; r[1] = (bf16_t)a.y; r[2] = (bf16_t)a.z; r[3] = (bf16_t)a.w;
    r[4] = (bf16_t)b.x; r[5] = (bf16_t)b.y; r[6] = (bf16_t)b.z; r[7] = (bf16_t)b.w;
    return r;
}

// device-coherent (LLC) 16B fragment read: two agent-scope relaxed 8B atomic loads
__device__ __forceinline__ bf16x8 frag_coh(const bf16_t* p) {
    union { u64 q[2]; bf16x8 v; } u;
    u.q[0] = __hip_atomic_load((u64*)(void*)p,       __ATOMIC_RELAXED, __HIP_MEMORY_SCOPE_AGENT);
    u.q[1] = __hip_atomic_load((u64*)(void*)(p + 4), __ATOMIC_RELAXED, __HIP_MEMORY_SCOPE_AGENT);
    return u.v;
}

// Wait until sum(L0 subcounters) >= thr0 && sum(L1 subcounters) >= thr1.
// Within-layer step spread is <=1 (every block also waits on its own layer),
// so the sum threshold is exactly equivalent to the min threshold.
__device__ __forceinline__ void wait_counts(unsigned* cnt, unsigned thr0, unsigned thr1,
                                            int tid, int lane) {
    if (tid < 64) {
        for (;;) {
            unsigned v = 0;
            if (lane < 2 * NCNT)
                v = __hip_atomic_load(&cnt[lane * FSTRIDE], __ATOMIC_RELAXED,
                                      __HIP_MEMORY_SCOPE_AGENT);
            unsigned s = v;
            s += __shfl_xor(s, 1);
            s += __shfl_xor(s, 2);
            s += __shfl_xor(s, 4);
            s += __shfl_xor(s, 8);            // sums within 16-lane groups
            unsigned S0 = __shfl(s, 0);       // lanes 0..15  -> layer-0 total
            unsigned S1 = __shfl(s, 16);      // lanes 16..31 -> layer-1 total
            if (S0 >= thr0 && S1 >= thr1) break;
            __builtin_amdgcn_s_sleep(4);
        }
    }
    __syncthreads();
}

// prep: zero progress counters, prefill bf16 h-rings (t = -1), optional x->bf16 shadow.
__global__ void prep_kernel(const float* __restrict__ x, const float* __restrict__ h0,
                            bf16_t* __restrict__ ring0, bf16_t* __restrict__ ring1,
                            bf16_t* __restrict__ x_sh, unsigned* __restrict__ cnt,
                            int use_xsh) {
    int gtid = blockIdx.x * blockDim.x + threadIdx.x;
    int gsz  = gridDim.x * blockDim.x;
    if (gtid < 2 * NCNT) cnt[gtid * FSTRIDE] = 0u;
    for (int i = gtid; i < BH; i += gsz) {
        ring0[(size_t)(R0 - 1) * BH + i] = (bf16_t)h0[i];         // h^0[-1] in slot R0-1
        ring1[(size_t)1 * BH + i]        = (bf16_t)h0[BH + i];    // h^1[-1] in slot 1
    }
    if (use_xsh) {
        int ngrp = S_LEN * BH / 8;
        for (int g = gtid; g < ngrp; g += gsz)
            *reinterpret_cast<bf16x8*>(x_sh + (size_t)g * 8) = cvt8(x + (size_t)g * 8);
    }
}

// Persistent fence-free pipelined LSTM.
// Block b: layer l=b>>7, unit-group ug8=b&127 (hidden units 8*ug8..8*ug8+7 -> 32 gate rows).
// LDS weights: [256 granules][32 rows] bf16x8 = 128 KB (granules 0-127 Wx, 128-255 Wh),
// conflict-free (lanes read consecutive rows).
// Waves: wv = 2*mt + kh; mt = M-tile (16 batches), kh = K-half (512 of 1024 per operand).
// Sync: per-layer monotonic sum-counters at LLC; ring data via agent-scope atomics;
// no cache fences in the loop.
__global__ __launch_bounds__(NTHR, 2) void lstm_persistent(
    const float* __restrict__ x,
    const float* __restrict__ c0,
    const float* __restrict__ Wx,
    const float* __restrict__ Wh,
    const float* __restrict__ bx,
    const float* __restrict__ bh,
    float* __restrict__ out,
    bf16_t* __restrict__ ring0,
    bf16_t* __restrict__ ring1,
    const bf16_t* __restrict__ x_sh,
    unsigned* __restrict__ cnt,
    int use_xsh)
{
    __shared__ __attribute__((aligned(16))) unsigned char lds_w[256 * 512];  // 128 KB
    __shared__ __attribute__((aligned(16))) float lds_red[8 * 256];          // 8 KB K-reduce
    __shared__ __attribute__((aligned(16))) float lds_hf[BATCH * 8];         // 2 KB h staging

    const int tid  = threadIdx.x;
    const int bid  = blockIdx.x;
    const int l    = bid >> 7;
    const int ug8  = bid & 127;
    const int lane = tid & 63;
    const int wv   = tid >> 6;
    const int mt   = wv >> 1;
    const int kh   = wv & 1;
    const int quad = lane >> 4;
    const int r16  = lane & 15;

    float* ys   = out;
    float* hfin = out + (size_t)S_LEN * BH;
    float* cfin = hfin + 2 * BH;

    // ---- stage this block's 32 weight rows (fp32 -> bf16) into LDS [gran][row] ----
    {
        const float* WxL = Wx + (size_t)l * G4 * HID;
        const float* WhL = Wh + (size_t)l * G4 * HID;
        for (int ch = tid; ch < 32 * 256; ch += NTHR) {
            int row = ch & 31;           // row = 4*unit_local + gate
            int gr  = ch >> 5;
            int ul = row >> 2, g = row & 3;
            size_t R = (size_t)g * HID + 8 * ug8 + ul;
            const float* src = (gr < 128) ? (WxL + R * HID + (size_t)gr * 8)
                                          : (WhL + R * HID + (size_t)(gr - 128) * 8);
            *reinterpret_cast<bf16x8*>(&lds_w[gr * 512 + row * 16]) = cvt8(src);
        }
    }

    const int b_loc  = lane >> 2;
    const int uu     = lane & 3;
    const int b_glob = 16 * mt + b_loc;
    const int u_loc  = 4 * kh + uu;          // this thread's unit within the 8
    const int u_glob = 8 * ug8 + u_loc;

    float bias_r[4];
    #pragma unroll
    for (int gi = 0; gi < 4; ++gi) {
        int R = gi * HID + u_glob;
        bias_r[gi] = bx[l * G4 + R] + bh[l * G4 + R];
    }
    float c_reg = c0[(size_t)l * BH + (size_t)b_glob * HID + u_glob];

    bf16_t* ringL = (l == 0) ? ring0 : ring1;
    unsigned* mycnt = &cnt[(l * NCNT + (ug8 & (NCNT - 1))) * FSTRIDE];
    __syncthreads();

    const int arow_off = (16 * mt + r16) * HID + kh * 512 + quad * 8;

    for (int t = 0; t < S_LEN; ++t) {
        f32x4 acc0 = {0.f, 0.f, 0.f, 0.f};
        f32x4 acc1 = {0.f, 0.f, 0.f, 0.f};

        if (l == 0) {
            // ---- x-part first: no cross-block dependency, overlaps the wait ----
            if (use_xsh) {
                const bf16_t* arow = x_sh + (size_t)t * BH + arow_off;
                #pragma unroll 8
                for (int ks = 0; ks < 16; ++ks) {
                    int gr = kh * 64 + ks * 4 + quad;
                    bf16x8 b0 = *reinterpret_cast<const bf16x8*>(&lds_w[gr * 512 + r16 * 16]);
                    bf16x8 b1 = *reinterpret_cast<const bf16x8*>(&lds_w[gr * 512 + (16 + r16) * 16]);
                    bf16x8 a  = *reinterpret_cast<const bf16x8*>(arow + ks * 32);
                    acc0 = __builtin_amdgcn_mfma_f32_16x16x32_bf16(a, b0, acc0, 0, 0, 0);
                    acc1 = __builtin_amdgcn_mfma_f32_16x16x32_bf16(a, b1, acc1, 0, 0, 0);
                }
            } else {
                const float* arow = x + (size_t)t * BH + arow_off;
                #pragma unroll 4
                for (int ks = 0; ks < 16; ++ks) {
                    int gr = kh * 64 + ks * 4 + quad;
                    bf16x8 b0 = *reinterpret_cast<const bf16x8*>(&lds_w[gr * 512 + r16 * 16]);
                    bf16x8 b1 = *reinterpret_cast<const bf16x8*>(&lds_w[gr * 512 + (16 + r16) * 16]);
                    bf16x8 a  = cvt8(arow + ks * 32);
                    acc0 = __builtin_amdgcn_mfma_f32_16x16x32_bf16(a, b0, acc0, 0, 0, 0);
                    acc1 = __builtin_amdgcn_mfma_f32_16x16x32_bf16(a, b1, acc1, 0, 0, 0);
                }
            }
            // need: all L0 published t-1; all L1 consumed ring0 slot we are about to write
            unsigned thr1 = (t > SKEW) ? (unsigned)(LBLK * (t - SKEW)) : 0u;
            wait_counts(cnt, (unsigned)(LBLK * t), thr1, tid, lane);
            // ---- h-part from ring0[t-1] ----
            const bf16_t* ah = ring0 + (size_t)((t - 1) & (R0 - 1)) * BH + arow_off;
            #pragma unroll 8
            for (int ks = 0; ks < 16; ++ks) {
                int gr = 128 + kh * 64 + ks * 4 + quad;
                bf16x8 b0 = *reinterpret_cast<const bf16x8*>(&lds_w[gr * 512 + r16 * 16]);
                bf16x8 b1 = *reinterpret_cast<const bf16x8*>(&lds_w[gr * 512 + (16 + r16) * 16]);
                bf16x8 a  = frag_coh(ah + ks * 32);
                acc0 = __builtin_amdgcn_mfma_f32_16x16x32_bf16(a, b0, acc0, 0, 0, 0);
                acc1 = __builtin_amdgcn_mfma_f32_16x16x32_bf16(a, b1, acc1, 0, 0, 0);
            }
        } else {
            // need: all L0 published t (x input); all L1 published t-1 (h input)
            wait_counts(cnt, (unsigned)(LBLK * (t + 1)), (unsigned)(LBLK * t), tid, lane);
            // ---- x-part from ring0[t] ----
            const bf16_t* ax = ring0 + (size_t)(t & (R0 - 1)) * BH + arow_off;
            #pragma unroll 8
            for (int ks = 0; ks < 16; ++ks) {
                int gr = kh * 64 + ks * 4 + quad;
                bf16x8 b0 = *reinterpret_cast<const bf16x8*>(&lds_w[gr * 512 + r16 * 16]);
                bf16x8 b1 = *reinterpret_cast<const bf16x8*>(&lds_w[gr * 512 + (16 + r16) * 16]);
                bf16x8 a  = frag_coh(ax + ks * 32);
                acc0 = __builtin_amdgcn_mfma_f32_16x16x32_bf16(a, b0, acc0, 0, 0, 0);
                acc1 = __builtin_amdgcn_mfma_f32_16x16x32_bf16(a, b1, acc1, 0, 0, 0);
            }
            // ---- h-part from ring1[t-1] ----
            const bf16_t* ah = ring1 + (size_t)((t - 1) & 1) * BH + arow_off;
            #pragma unroll 8
            for (int ks = 0; ks < 16; ++ks) {
                int gr = 128 + kh * 64 + ks * 4 + quad;
                bf16x8 b0 = *reinterpret_cast<const bf16x8*>(&lds_w[gr * 512 + r16 * 16]);
                bf16x8 b1 = *reinterpret_cast<const bf16x8*>(&lds_w[gr * 512 + (16 + r16) * 16]);
                bf16x8 a  = frag_coh(ah + ks * 32);
                acc0 = __builtin_amdgcn_mfma_f32_16x16x32_bf16(a, b0, acc0, 0, 0, 0);
                acc1 = __builtin_amdgcn_mfma_f32_16x16x32_bf16(a, b1, acc1, 0, 0, 0);
            }
        }

        // ---- K-half reduce: wave (mt,kh) keeps N-tile kh, ships the other ----
        {
            f32x4 ship = kh ? acc0 : acc1;
            *reinterpret_cast<f32x4*>(&lds_red[wv * 256 + lane * 4]) = ship;
            __syncthreads();
            f32x4 part = *reinterpret_cast<const f32x4*>(&lds_red[(wv ^ 1) * 256 + lane * 4]);
            f32x4 keep = kh ? acc1 : acc0;
            acc0 = keep + part;        // final C tile: batches of mt x gate-rows of N-tile kh
        }

        // ---- gather 4 gates for (b_loc, uu); C layout: col=lane&15, row=quad*4+reg ----
        {
            const int quad_s = b_loc >> 2;
            const int reg_s  = b_loc & 3;
            float gsum[4];
            #pragma unroll
            for (int gi = 0; gi < 4; ++gi) {
                int lane_s = (quad_s << 4) | (4 * uu + gi);
                float v0 = __shfl(acc0[0], lane_s, 64);
                float v1 = __shfl(acc0[1], lane_s, 64);
                float v2 = __shfl(acc0[2], lane_s, 64);
                float v3 = __shfl(acc0[3], lane_s, 64);
                float v  = (reg_s == 0) ? v0 : (reg_s == 1) ? v1 : (reg_s == 2) ? v2 : v3;
                gsum[gi] = v + bias_r[gi];
            }
            float fg = sigmoid_f(gsum[0]);
            float ig = sigmoid_f(gsum[1]);
            float og = sigmoid_f(gsum[2]);
            float cx = tanh_f(gsum[3]);
            float cN = fg * c_reg + ig * cx;
            float h  = og * tanh_f(cN);
            c_reg = cN;
            lds_hf[b_glob * 8 + u_loc] = h;
            if (t == S_LEN - 1) {
                hfin[(size_t)l * BH + (size_t)b_glob * HID + u_glob] = h;
                cfin[(size_t)l * BH + (size_t)b_glob * HID + u_glob] = cN;
            }
        }
        __syncthreads();

        // ---- publish: wave 0 stores 64 batches x 8 units via coherent 8B stores ----
        if (tid < 64) {
            const float* hp = &lds_hf[lane * 8];
            union { bf16x4 v; u64 q; } p0, p1;
            #pragma unroll
            for (int j = 0; j < 4; ++j) {
                p0.v[j] = (bf16_t)hp[j];
                p1.v[j] = (bf16_t)hp[4 + j];
            }
            const int slotmask = (l == 0) ? (R0 - 1) : 1;
            bf16_t* dst = ringL + (size_t)(t & slotmask) * BH + (size_t)lane * HID + 8 * ug8;
            __hip_atomic_store((u64*)(void*)dst,       p0.q, __ATOMIC_RELAXED, __HIP_MEMORY_SCOPE_AGENT);
            __hip_atomic_store((u64*)(void*)(dst + 4), p1.q, __ATOMIC_RELAXED, __HIP_MEMORY_SCOPE_AGENT);
            if (l == 1) {
                float* yd = ys + (size_t)t * BH + (size_t)lane * HID + 8 * ug8;
                __builtin_nontemporal_store(*reinterpret_cast<const f32x4*>(hp),     reinterpret_cast<f32x4*>(yd));
                __builtin_nontemporal_store(*reinterpret_cast<const f32x4*>(hp + 4), reinterpret_cast<f32x4*>(yd + 4));
            }
            asm volatile("s_waitcnt vmcnt(0)" ::: "memory");  // data at LLC before progress tick
            if (lane == 0) atomicAdd(mycnt, 1u);
        }
    }
}

extern "C" void kernel_launch(void* const* d_in, const int* in_sizes, int n_in,
                              void* d_out, int out_size, void* d_ws, size_t ws_size,
                              hipStream_t stream) {
    (void)in_sizes; (void)n_in; (void)out_size;
    const float* x  = (const float*)d_in[0];
    const float* h0 = (const float*)d_in[1];
    const float* c0 = (const float*)d_in[2];
    const float* Wx = (const float*)d_in[3];
    const float* Wh = (const float*)d_in[4];
    const float* bx = (const float*)d_in[5];
    const float* bh = (const float*)d_in[6];

    unsigned char* ws = (unsigned char*)d_ws;
    unsigned* cnt = (unsigned*)ws;                                    // 32 counters, 128 B apart
    size_t off = 32768;
    bf16_t* ring0 = (bf16_t*)(ws + off); off += (size_t)R0 * BH * 2;  // 1 MB
    bf16_t* ring1 = (bf16_t*)(ws + off); off += (size_t)2 * BH * 2;   // 256 KB
    bf16_t* x_sh  = (bf16_t*)(ws + off);
    size_t need_xsh = off + (size_t)S_LEN * BH * 2;                   // + 64 MB
    int use_xsh = (ws_size >= need_xsh) ? 1 : 0;

    prep_kernel<<<2048, 256, 0, stream>>>(x, h0, ring0, ring1, x_sh, cnt, use_xsh);
    lstm_persistent<<<NBLK, NTHR, 0, stream>>>(x, c0, Wx, Wh, bx, bh, (float*)d_out,
                                               ring0, ring1, x_sh, cnt, use_xsh);
}

// Round 2
// 6727.332 us; speedup vs baseline: 2.6366x; 1.3919x over previous
//
#include <hip/hip_runtime.h>

typedef __bf16 bf16_t;
typedef __bf16 bf16x8 __attribute__((ext_vector_type(8)));
typedef __bf16 bf16x4 __attribute__((ext_vector_type(4)));
typedef float  f32x4  __attribute__((ext_vector_type(4)));
typedef unsigned long long u64;

#define S_LEN 512
#define BATCH 64
#define HID 1024
#define BH (BATCH*HID)          /* 65536 */
#define G4 (4*HID)
#define NBLK 256                /* 128 layer-0 + 128 layer-1, 1 block/CU */
#define LBLK 128                /* blocks per layer */
#define NTHR 512                /* 8 waves: 4 M-tiles x 2 K-halves */
#define R0 8                    /* ring0 slots (L0->L1 skew budget) */
#define SKEW (R0-1)
#define FSTRIDE 32              /* counter spacing: 128 B */
#define NCNT 16                 /* sub-counters per layer */

__device__ __forceinline__ float sigmoid_f(float x) { return 1.f / (1.f + __expf(-x)); }
__device__ __forceinline__ float tanh_f(float x) {
    float e = __expf(-2.f * fabsf(x));
    float t = (1.f - e) / (1.f + e);
    return x >= 0.f ? t : -t;
}

__device__ __forceinline__ bf16x8 cvt8(const float* p) {
    float4 a = *reinterpret_cast<const float4*>(p);
    float4 b = *reinterpret_cast<const float4*>(p + 4);
    bf16x8 r;
    r[0] = (bf16_t)a.x; r[1] = (bf16_t)a.y; r[2] = (bf16_t)a.z; r[3] = (bf16_t)a.w;
    r[4] = (bf16_t)b.x; r[5] = (bf16_t)b.y; r[6] = (bf16_t)b.z; r[7] = (bf16_t)b.w;
    return r;
}

// Wait until sum(L0 subcounters) >= thr0 && sum(L1 subcounters) >= thr1, then
// acquire-fence (L1/L2 invalidate) so subsequent CACHED ring reads see LLC data.
// Within-layer step spread is <=1, so sum threshold == min threshold.
__device__ __forceinline__ void wait_counts(unsigned* cnt, unsigned thr0, unsigned thr1,
                                            int tid, int lane) {
    if (tid < 64) {
        for (;;) {
            unsigned v = 0;
            if (lane < 2 * NCNT)
                v = __hip_atomic_load(&cnt[lane * FSTRIDE], __ATOMIC_RELAXED,
                                      __HIP_MEMORY_SCOPE_AGENT);
            unsigned s = v;
            s += __shfl_xor(s, 1);
            s += __shfl_xor(s, 2);
            s += __shfl_xor(s, 4);
            s += __shfl_xor(s, 8);            // sums within 16-lane groups
            unsigned S0 = __shfl(s, 0);       // lanes 0..15  -> layer-0 total
            unsigned S1 = __shfl(s, 16);      // lanes 16..31 -> layer-1 total
            if (S0 >= thr0 && S1 >= thr1) break;
            __builtin_amdgcn_s_sleep(4);
        }
        // invalidate L1+L2 so cached ring loads refetch from LLC (coherence point).
        // Writers publish write-through (sc1 atomic stores) -> no dirty ring lines anywhere.
        __builtin_amdgcn_fence(__ATOMIC_ACQUIRE, "agent");
    }
    __syncthreads();
}

// prep: zero progress counters, prefill bf16 h-rings (t = -1), optional x->bf16 shadow.
__global__ void prep_kernel(const float* __restrict__ x, const float* __restrict__ h0,
                            bf16_t* __restrict__ ring0, bf16_t* __restrict__ ring1,
                            bf16_t* __restrict__ x_sh, unsigned* __restrict__ cnt,
                            int use_xsh) {
    int gtid = blockIdx.x * blockDim.x + threadIdx.x;
    int gsz  = gridDim.x * blockDim.x;
    if (gtid < 2 * NCNT) cnt[gtid * FSTRIDE] = 0u;
    for (int i = gtid; i < BH; i += gsz) {
        ring0[(size_t)(R0 - 1) * BH + i] = (bf16_t)h0[i];         // h^0[-1] in slot R0-1
        ring1[(size_t)1 * BH + i]        = (bf16_t)h0[BH + i];    // h^1[-1] in slot 1
    }
    if (use_xsh) {
        int ngrp = S_LEN * BH / 8;
        for (int g = gtid; g < ngrp; g += gsz)
            *reinterpret_cast<bf16x8*>(x_sh + (size_t)g * 8) = cvt8(x + (size_t)g * 8);
    }
}

// Persistent pipelined LSTM, L2-cached broadcast.
// Block b: layer l=b>>7, unit-group ug8=b&127 (hidden units 8*ug8..8*ug8+7 -> 32 gate rows).
// LDS weights: [256 granules][32 rows] bf16x8 = 128 KB (granules 0-127 Wx, 128-255 Wh).
// Waves: wv = 2*mt + kh; mt = M-tile (16 batches), kh = K-half (512 of 1024 per operand).
// Sync: per-layer sum-counters at LLC (sc1 atomics); ring data published write-through,
// read via NORMAL cached loads after a per-step agent-acquire (buffer_inv).
__global__ __launch_bounds__(NTHR, 2) void lstm_persistent(
    const float* __restrict__ x,
    const float* __restrict__ c0,
    const float* __restrict__ Wx,
    const float* __restrict__ Wh,
    const float* __restrict__ bx,
    const float* __restrict__ bh,
    float* __restrict__ out,
    bf16_t* __restrict__ ring0,
    bf16_t* __restrict__ ring1,
    const bf16_t* __restrict__ x_sh,
    unsigned* __restrict__ cnt,
    int use_xsh)
{
    __shared__ __attribute__((aligned(16))) unsigned char lds_w[256 * 512];  // 128 KB
    __shared__ __attribute__((aligned(16))) float lds_red[8 * 256];          // 8 KB K-reduce
    __shared__ __attribute__((aligned(16))) float lds_hf[BATCH * 8];         // 2 KB h staging

    const int tid  = threadIdx.x;
    const int bid  = blockIdx.x;
    const int l    = bid >> 7;
    const int ug8  = bid & 127;
    const int lane = tid & 63;
    const int wv   = tid >> 6;
    const int mt   = wv >> 1;
    const int kh   = wv & 1;
    const int quad = lane >> 4;
    const int r16  = lane & 15;

    float* ys   = out;
    float* hfin = out + (size_t)S_LEN * BH;
    float* cfin = hfin + 2 * BH;

    // ---- stage this block's 32 weight rows (fp32 -> bf16) into LDS [gran][row] ----
    {
        const float* WxL = Wx + (size_t)l * G4 * HID;
        const float* WhL = Wh + (size_t)l * G4 * HID;
        for (int ch = tid; ch < 32 * 256; ch += NTHR) {
            int row = ch & 31;           // row = 4*unit_local + gate
            int gr  = ch >> 5;
            int ul = row >> 2, g = row & 3;
            size_t R = (size_t)g * HID + 8 * ug8 + ul;
            const float* src = (gr < 128) ? (WxL + R * HID + (size_t)gr * 8)
                                          : (WhL + R * HID + (size_t)(gr - 128) * 8);
            *reinterpret_cast<bf16x8*>(&lds_w[gr * 512 + row * 16]) = cvt8(src);
        }
    }

    const int b_loc  = lane >> 2;
    const int uu     = lane & 3;
    const int b_glob = 16 * mt + b_loc;
    const int u_loc  = 4 * kh + uu;          // this thread's unit within the 8
    const int u_glob = 8 * ug8 + u_loc;

    float bias_r[4];
    #pragma unroll
    for (int gi = 0; gi < 4; ++gi) {
        int R = gi * HID + u_glob;
        bias_r[gi] = bx[l * G4 + R] + bh[l * G4 + R];
    }
    float c_reg = c0[(size_t)l * BH + (size_t)b_glob * HID + u_glob];

    bf16_t* ringL = (l == 0) ? ring0 : ring1;
    unsigned* mycnt = &cnt[(l * NCNT + (ug8 & (NCNT - 1))) * FSTRIDE];
    __syncthreads();

    const int arow_off = (16 * mt + r16) * HID + kh * 512 + quad * 8;

    for (int t = 0; t < S_LEN; ++t) {
        f32x4 acc0 = {0.f, 0.f, 0.f, 0.f};
        f32x4 acc1 = {0.f, 0.f, 0.f, 0.f};

        if (l == 0) {
            // ---- x-part first: no cross-block dependency, overlaps the wait ----
            bf16x8 af[16];
            if (use_xsh) {
                const bf16_t* arow = x_sh + (size_t)t * BH + arow_off;
                #pragma unroll
                for (int ks = 0; ks < 16; ++ks)
                    af[ks] = *reinterpret_cast<const bf16x8*>(arow + ks * 32);
            } else {
                const float* arow = x + (size_t)t * BH + arow_off;
                #pragma unroll
                for (int ks = 0; ks < 16; ++ks)
                    af[ks] = cvt8(arow + ks * 32);
            }
            #pragma unroll
            for (int ks = 0; ks < 16; ++ks) {
                int gr = kh * 64 + ks * 4 + quad;
                bf16x8 b0 = *reinterpret_cast<const bf16x8*>(&lds_w[gr * 512 + r16 * 16]);
                bf16x8 b1 = *reinterpret_cast<const bf16x8*>(&lds_w[gr * 512 + (16 + r16) * 16]);
                acc0 = __builtin_amdgcn_mfma_f32_16x16x32_bf16(af[ks], b0, acc0, 0, 0, 0);
                acc1 = __builtin_amdgcn_mfma_f32_16x16x32_bf16(af[ks], b1, acc1, 0, 0, 0);
            }
            // need: all L0 published t-1; all L1 consumed ring0 slot we are about to write
            unsigned thr1 = (t > SKEW) ? (unsigned)(LBLK * (t - SKEW)) : 0u;
            wait_counts(cnt, (unsigned)(LBLK * t), thr1, tid, lane);
            // ---- h-part from ring0[t-1], cached loads, all in flight ----
            const bf16_t* ah = ring0 + (size_t)((t - 1) & (R0 - 1)) * BH + arow_off;
            #pragma unroll
            for (int ks = 0; ks < 16; ++ks)
                af[ks] = *reinterpret_cast<const bf16x8*>(ah + ks * 32);
            #pragma unroll
            for (int ks = 0; ks < 16; ++ks) {
                int gr = 128 + kh * 64 + ks * 4 + quad;
                bf16x8 b0 = *reinterpret_cast<const bf16x8*>(&lds_w[gr * 512 + r16 * 16]);
                bf16x8 b1 = *reinterpret_cast<const bf16x8*>(&lds_w[gr * 512 + (16 + r16) * 16]);
                acc0 = __builtin_amdgcn_mfma_f32_16x16x32_bf16(af[ks], b0, acc0, 0, 0, 0);
                acc1 = __builtin_amdgcn_mfma_f32_16x16x32_bf16(af[ks], b1, acc1, 0, 0, 0);
            }
        } else {
            // need: all L0 published t (x input); all L1 published t-1 (h input)
            wait_counts(cnt, (unsigned)(LBLK * (t + 1)), (unsigned)(LBLK * t), tid, lane);
            const bf16_t* ax = ring0 + (size_t)(t & (R0 - 1)) * BH + arow_off;
            const bf16_t* ah = ring1 + (size_t)((t - 1) & 1) * BH + arow_off;
            // ---- issue ALL 32 cached loads (both phases) before the MFMA chains ----
            bf16x8 axf[16], ahf[16];
            #pragma unroll
            for (int ks = 0; ks < 16; ++ks)
                axf[ks] = *reinterpret_cast<const bf16x8*>(ax + ks * 32);
            #pragma unroll
            for (int ks = 0; ks < 16; ++ks)
                ahf[ks] = *reinterpret_cast<const bf16x8*>(ah + ks * 32);
            #pragma unroll
            for (int ks = 0; ks < 16; ++ks) {
                int gr = kh * 64 + ks * 4 + quad;
                bf16x8 b0 = *reinterpret_cast<const bf16x8*>(&lds_w[gr * 512 + r16 * 16]);
                bf16x8 b1 = *reinterpret_cast<const bf16x8*>(&lds_w[gr * 512 + (16 + r16) * 16]);
                acc0 = __builtin_amdgcn_mfma_f32_16x16x32_bf16(axf[ks], b0, acc0, 0, 0, 0);
                acc1 = __builtin_amdgcn_mfma_f32_16x16x32_bf16(axf[ks], b1, acc1, 0, 0, 0);
            }
            #pragma unroll
            for (int ks = 0; ks < 16; ++ks) {
                int gr = 128 + kh * 64 + ks * 4 + quad;
                bf16x8 b0 = *reinterpret_cast<const bf16x8*>(&lds_w[gr * 512 + r16 * 16]);
                bf16x8 b1 = *reinterpret_cast<const bf16x8*>(&lds_w[gr * 512 + (16 + r16) * 16]);
                acc0 = __builtin_amdgcn_mfma_f32_16x16x32_bf16(ahf[ks], b0, acc0, 0, 0, 0);
                acc1 = __builtin_amdgcn_mfma_f32_16x16x32_bf16(ahf[ks], b1, acc1, 0, 0, 0);
            }
        }

        // ---- K-half reduce: wave (mt,kh) keeps N-tile kh, ships the other ----
        {
            f32x4 ship = kh ? acc0 : acc1;
            *reinterpret_cast<f32x4*>(&lds_red[wv * 256 + lane * 4]) = ship;
            __syncthreads();
            f32x4 part = *reinterpret_cast<const f32x4*>(&lds_red[(wv ^ 1) * 256 + lane * 4]);
            f32x4 keep = kh ? acc1 : acc0;
            acc0 = keep + part;        // final C tile: batches of mt x gate-rows of N-tile kh
        }

        // ---- gather 4 gates for (b_loc, uu); C layout: col=lane&15, row=quad*4+reg ----
        {
            const int quad_s = b_loc >> 2;
            const int reg_s  = b_loc & 3;
            float gsum[4];
            #pragma unroll
            for (int gi = 0; gi < 4; ++gi) {
                int lane_s = (quad_s << 4) | (4 * uu + gi);
                float v0 = __shfl(acc0[0], lane_s, 64);
                float v1 = __shfl(acc0[1], lane_s, 64);
                float v2 = __shfl(acc0[2], lane_s, 64);
                float v3 = __shfl(acc0[3], lane_s, 64);
                float v  = (reg_s == 0) ? v0 : (reg_s == 1) ? v1 : (reg_s == 2) ? v2 : v3;
                gsum[gi] = v + bias_r[gi];
            }
            float fg = sigmoid_f(gsum[0]);
            float ig = sigmoid_f(gsum[1]);
            float og = sigmoid_f(gsum[2]);
            float cx = tanh_f(gsum[3]);
            float cN = fg * c_reg + ig * cx;
            float h  = og * tanh_f(cN);
            c_reg = cN;
            lds_hf[b_glob * 8 + u_loc] = h;
            if (t == S_LEN - 1) {
                hfin[(size_t)l * BH + (size_t)b_glob * HID + u_glob] = h;
                cfin[(size_t)l * BH + (size_t)b_glob * HID + u_glob] = cN;
            }
        }
        __syncthreads();

        // ---- publish: wave 0 stores 64 batches x 8 units, write-through to LLC ----
        if (tid < 64) {
            const float* hp = &lds_hf[lane * 8];
            union { bf16x4 v; u64 q; } p0, p1;
            #pragma unroll
            for (int j = 0; j < 4; ++j) {
                p0.v[j] = (bf16_t)hp[j];
                p1.v[j] = (bf16_t)hp[4 + j];
            }
            const int slotmask = (l == 0) ? (R0 - 1) : 1;
            bf16_t* dst = ringL + (size_t)(t & slotmask) * BH + (size_t)lane * HID + 8 * ug8;
            __hip_atomic_store((u64*)(void*)dst,       p0.q, __ATOMIC_RELAXED, __HIP_MEMORY_SCOPE_AGENT);
            __hip_atomic_store((u64*)(void*)(dst + 4), p1.q, __ATOMIC_RELAXED, __HIP_MEMORY_SCOPE_AGENT);
            if (l == 1) {
                float* yd = ys + (size_t)t * BH + (size_t)lane * HID + 8 * ug8;
                __builtin_nontemporal_store(*reinterpret_cast<const f32x4*>(hp),     reinterpret_cast<f32x4*>(yd));
                __builtin_nontemporal_store(*reinterpret_cast<const f32x4*>(hp + 4), reinterpret_cast<f32x4*>(yd + 4));
            }
            asm volatile("s_waitcnt vmcnt(0)" ::: "memory");  // data at LLC before progress tick
            if (lane == 0) atomicAdd(mycnt, 1u);
        }
    }
}

extern "C" void kernel_launch(void* const* d_in, const int* in_sizes, int n_in,
                              void* d_out, int out_size, void* d_ws, size_t ws_size,
                              hipStream_t stream) {
    (void)in_sizes; (void)n_in; (void)out_size;
    const float* x  = (const float*)d_in[0];
    const float* h0 = (const float*)d_in[1];
    const float* c0 = (const float*)d_in[2];
    const float* Wx = (const float*)d_in[3];
    const float* Wh = (const float*)d_in[4];
    const float* bx = (const float*)d_in[5];
    const float* bh = (const float*)d_in[6];

    unsigned char* ws = (unsigned char*)d_ws;
    unsigned* cnt = (unsigned*)ws;                                    // 32 counters, 128 B apart
    size_t off = 32768;
    bf16_t* ring0 = (bf16_t*)(ws + off); off += (size_t)R0 * BH * 2;  // 1 MB
    bf16_t* ring1 = (bf16_t*)(ws + off); off += (size_t)2 * BH * 2;   // 256 KB
    bf16_t* x_sh  = (bf16_t*)(ws + off);
    size_t need_xsh = off + (size_t)S_LEN * BH * 2;                   // + 64 MB
    int use_xsh = (ws_size >= need_xsh) ? 1 : 0;

    prep_kernel<<<2048, 256, 0, stream>>>(x, h0, ring0, ring1, x_sh, cnt, use_xsh);
    lstm_persistent<<<NBLK, NTHR, 0, stream>>>(x, c0, Wx, Wh, bx, bh, (float*)d_out,
                                               ring0, ring1, x_sh, cnt, use_xsh);
}

// Round 3
// 6660.703 us; speedup vs baseline: 2.6630x; 1.0100x over previous
//
#include <hip/hip_runtime.h>

typedef __bf16 bf16_t;
typedef __bf16 bf16x8 __attribute__((ext_vector_type(8)));
typedef __bf16 bf16x4 __attribute__((ext_vector_type(4)));
typedef float  f32x4  __attribute__((ext_vector_type(4)));
typedef unsigned long long u64;

#define S_LEN 512
#define BATCH 64
#define HID 1024
#define BH (BATCH*HID)          /* 65536 */
#define G4 (4*HID)
#define NBLK 256                /* 128 layer-0 + 128 layer-1, 1 block/CU */
#define LBLK 128                /* blocks per layer */
#define NTHR 512                /* 8 waves: 4 M-tiles x 2 K-halves */
#define FSTRIDE 32              /* counter spacing: 128 B */
#define NCNT 16                 /* sub-counters per layer */
#define RSKEW 7                 /* fallback-mode ring skew */

__device__ __forceinline__ float sigmoid_f(float x) { return 1.f / (1.f + __expf(-x)); }
__device__ __forceinline__ float tanh_f(float x) {
    float e = __expf(-2.f * fabsf(x));
    float t = (1.f - e) / (1.f + e);
    return x >= 0.f ? t : -t;
}

__device__ __forceinline__ bf16x8 cvt8(const float* p) {
    float4 a = *reinterpret_cast<const float4*>(p);
    float4 b = *reinterpret_cast<const float4*>(p + 4);
    bf16x8 r;
    r[0] = (bf16_t)a.x; r[1] = (bf16_t)a.y; r[2] = (bf16_t)a.z; r[3] = (bf16_t)a.w;
    r[4] = (bf16_t)b.x; r[5] = (bf16_t)b.y; r[6] = (bf16_t)b.z; r[7] = (bf16_t)b.w;
    return r;
}

// Poll one layer's 16 sub-counters until their sum >= thr. No fence.
__device__ __forceinline__ void wait_one(unsigned* cnt, int layer, unsigned thr,
                                         int tid, int lane) {
    if (tid < 64) {
        for (;;) {
            unsigned v = 0;
            if (lane < NCNT)
                v = __hip_atomic_load(&cnt[(layer * NCNT + lane) * FSTRIDE],
                                      __ATOMIC_RELAXED, __HIP_MEMORY_SCOPE_AGENT);
            unsigned s = v;
            s += __shfl_xor(s, 1);
            s += __shfl_xor(s, 2);
            s += __shfl_xor(s, 4);
            s += __shfl_xor(s, 8);
            if (__shfl(s, 0) >= thr) break;
            __builtin_amdgcn_s_sleep(1);
        }
    }
    __syncthreads();
}

// Fallback (ring) mode: combined wait on both layers + acquire fence (L1/L2 inv).
__device__ __forceinline__ void wait_two_fence(unsigned* cnt, unsigned thr0, unsigned thr1,
                                               int tid, int lane) {
    if (tid < 64) {
        for (;;) {
            unsigned v = 0;
            if (lane < 2 * NCNT)
                v = __hip_atomic_load(&cnt[lane * FSTRIDE], __ATOMIC_RELAXED,
                                      __HIP_MEMORY_SCOPE_AGENT);
            unsigned s = v;
            s += __shfl_xor(s, 1);
            s += __shfl_xor(s, 2);
            s += __shfl_xor(s, 4);
            s += __shfl_xor(s, 8);
            unsigned S0 = __shfl(s, 0);
            unsigned S1 = __shfl(s, 16);
            if (S0 >= thr0 && S1 >= thr1) break;
            __builtin_amdgcn_s_sleep(1);
        }
        __builtin_amdgcn_fence(__ATOMIC_ACQUIRE, "agent");
    }
    __syncthreads();
}

// prep: zero progress counters, prefill bf16 h-buffers (t = -1 slot = mask).
__global__ void prep_kernel(const float* __restrict__ h0,
                            bf16_t* __restrict__ h0buf, bf16_t* __restrict__ h1buf,
                            unsigned* __restrict__ cnt, int mask0, int mask1) {
    int gtid = blockIdx.x * blockDim.x + threadIdx.x;
    int gsz  = gridDim.x * blockDim.x;
    if (gtid < 2 * NCNT) cnt[gtid * FSTRIDE] = 0u;
    for (int i = gtid; i < BH; i += gsz) {
        h0buf[(size_t)mask0 * BH + i] = (bf16_t)h0[i];
        h1buf[(size_t)mask1 * BH + i] = (bf16_t)h0[BH + i];
    }
}

// Persistent pipelined LSTM with fence-free L2-cached broadcast (ff mode).
// Block b: layer l=b>>7, unit-group ug8=b&127 (8 hidden units -> 32 gate rows).
// LDS weights: [256 granules][32 rows] bf16x8 = 128 KB (0-127 Wx, 128-255 Wh).
// Waves: wv = 2*mt + kh; mt = M-tile (16 batches), kh = K-half.
// ff=1: h published to per-step-unique slots (no address reuse) -> consumers'
// L2 first-touch fill is always fresh; NO cache fences. ff=0: ring+fence fallback.
__global__ __launch_bounds__(NTHR, 2) void lstm_persistent(
    const float* __restrict__ x,
    const float* __restrict__ c0,
    const float* __restrict__ Wx,
    const float* __restrict__ Wh,
    const float* __restrict__ bx,
    const float* __restrict__ bh,
    float* __restrict__ out,
    bf16_t* __restrict__ h0buf,
    bf16_t* __restrict__ h1buf,
    unsigned* __restrict__ cnt,
    int ff, int mask0, int mask1)
{
    __shared__ __attribute__((aligned(16))) unsigned char lds_w[256 * 512];  // 128 KB
    __shared__ __attribute__((aligned(16))) float lds_red[8 * 256];          // 8 KB K-reduce
    __shared__ __attribute__((aligned(16))) float lds_hf[BATCH * 8];         // 2 KB h staging

    const int tid  = threadIdx.x;
    const int bid  = blockIdx.x;
    const int l    = bid >> 7;
    const int ug8  = bid & 127;
    const int lane = tid & 63;
    const int wv   = tid >> 6;
    const int mt   = wv >> 1;
    const int kh   = wv & 1;
    const int quad = lane >> 4;
    const int r16  = lane & 15;

    float* ys   = out;
    float* hfin = out + (size_t)S_LEN * BH;
    float* cfin = hfin + 2 * BH;

    // ---- stage this block's 32 weight rows (fp32 -> bf16) into LDS [gran][row] ----
    {
        const float* WxL = Wx + (size_t)l * G4 * HID;
        const float* WhL = Wh + (size_t)l * G4 * HID;
        for (int ch = tid; ch < 32 * 256; ch += NTHR) {
            int row = ch & 31;           // row = 4*unit_local + gate
            int gr  = ch >> 5;
            int ul = row >> 2, g = row & 3;
            size_t R = (size_t)g * HID + 8 * ug8 + ul;
            const float* src = (gr < 128) ? (WxL + R * HID + (size_t)gr * 8)
                                          : (WhL + R * HID + (size_t)(gr - 128) * 8);
            *reinterpret_cast<bf16x8*>(&lds_w[gr * 512 + row * 16]) = cvt8(src);
        }
    }

    const int b_loc  = lane >> 2;
    const int uu     = lane & 3;
    const int b_glob = 16 * mt + b_loc;
    const int u_loc  = 4 * kh + uu;
    const int u_glob = 8 * ug8 + u_loc;

    float bias_r[4];
    #pragma unroll
    for (int gi = 0; gi < 4; ++gi) {
        int R = gi * HID + u_glob;
        bias_r[gi] = bx[l * G4 + R] + bh[l * G4 + R];
    }
    float c_reg = c0[(size_t)l * BH + (size_t)b_glob * HID + u_glob];

    bf16_t* pubbuf = (l == 0) ? h0buf : h1buf;
    const int pubmask = (l == 0) ? mask0 : mask1;
    unsigned* mycnt = &cnt[(l * NCNT + (ug8 & (NCNT - 1))) * FSTRIDE];
    __syncthreads();

    const int arow_off = (16 * mt + r16) * HID + kh * 512 + quad * 8;

    // L0: prefetch x fragments for t=0 into registers
    bf16x8 axp[16];
    if (l == 0) {
        const float* arow = x + arow_off;
        #pragma unroll
        for (int ks = 0; ks < 16; ++ks) axp[ks] = cvt8(arow + ks * 32);
    }

    for (int t = 0; t < S_LEN; ++t) {
        f32x4 acc0 = {0.f, 0.f, 0.f, 0.f};
        f32x4 acc1 = {0.f, 0.f, 0.f, 0.f};

        if (l == 0) {
            // ---- x-part from prefetched registers (no cross-block dependency) ----
            #pragma unroll
            for (int ks = 0; ks < 16; ++ks) {
                int gr = kh * 64 + ks * 4 + quad;
                bf16x8 b0 = *reinterpret_cast<const bf16x8*>(&lds_w[gr * 512 + r16 * 16]);
                bf16x8 b1 = *reinterpret_cast<const bf16x8*>(&lds_w[gr * 512 + (16 + r16) * 16]);
                acc0 = __builtin_amdgcn_mfma_f32_16x16x32_bf16(axp[ks], b0, acc0, 0, 0, 0);
                acc1 = __builtin_amdgcn_mfma_f32_16x16x32_bf16(axp[ks], b1, acc1, 0, 0, 0);
            }
            if (ff) {
                wait_one(cnt, 0, (unsigned)(LBLK * t), tid, lane);          // own layer at t-1
            } else {
                unsigned thr1 = (t > RSKEW) ? (unsigned)(LBLK * (t - RSKEW)) : 0u;
                wait_two_fence(cnt, (unsigned)(LBLK * t), thr1, tid, lane); // + slot-reuse check
            }
            // ---- h-part from h0buf[t-1], cached loads ----
            const bf16_t* ah = h0buf + (size_t)((t - 1) & mask0) * BH + arow_off;
            bf16x8 af[16];
            #pragma unroll
            for (int ks = 0; ks < 16; ++ks)
                af[ks] = *reinterpret_cast<const bf16x8*>(ah + ks * 32);
            #pragma unroll
            for (int ks = 0; ks < 16; ++ks) {
                int gr = 128 + kh * 64 + ks * 4 + quad;
                bf16x8 b0 = *reinterpret_cast<const bf16x8*>(&lds_w[gr * 512 + r16 * 16]);
                bf16x8 b1 = *reinterpret_cast<const bf16x8*>(&lds_w[gr * 512 + (16 + r16) * 16]);
                acc0 = __builtin_amdgcn_mfma_f32_16x16x32_bf16(af[ks], b0, acc0, 0, 0, 0);
                acc1 = __builtin_amdgcn_mfma_f32_16x16x32_bf16(af[ks], b1, acc1, 0, 0, 0);
            }
        } else {
            if (ff) {
                // ---- wait L0 published t, compute x-part, then wait own layer ----
                wait_one(cnt, 0, (unsigned)(LBLK * (t + 1)), tid, lane);
                const bf16_t* ax = h0buf + (size_t)(t & mask0) * BH + arow_off;
                bf16x8 axf[16];
                #pragma unroll
                for (int ks = 0; ks < 16; ++ks)
                    axf[ks] = *reinterpret_cast<const bf16x8*>(ax + ks * 32);
                #pragma unroll
                for (int ks = 0; ks < 16; ++ks) {
                    int gr = kh * 64 + ks * 4 + quad;
                    bf16x8 b0 = *reinterpret_cast<const bf16x8*>(&lds_w[gr * 512 + r16 * 16]);
                    bf16x8 b1 = *reinterpret_cast<const bf16x8*>(&lds_w[gr * 512 + (16 + r16) * 16]);
                    acc0 = __builtin_amdgcn_mfma_f32_16x16x32_bf16(axf[ks], b0, acc0, 0, 0, 0);
                    acc1 = __builtin_amdgcn_mfma_f32_16x16x32_bf16(axf[ks], b1, acc1, 0, 0, 0);
                }
                wait_one(cnt, 1, (unsigned)(LBLK * t), tid, lane);
                const bf16_t* ah = h1buf + (size_t)((t - 1) & mask1) * BH + arow_off;
                bf16x8 ahf[16];
                #pragma unroll
                for (int ks = 0; ks < 16; ++ks)
                    ahf[ks] = *reinterpret_cast<const bf16x8*>(ah + ks * 32);
                #pragma unroll
                for (int ks = 0; ks < 16; ++ks) {
                    int gr = 128 + kh * 64 + ks * 4 + quad;
                    bf16x8 b0 = *reinterpret_cast<const bf16x8*>(&lds_w[gr * 512 + r16 * 16]);
                    bf16x8 b1 = *reinterpret_cast<const bf16x8*>(&lds_w[gr * 512 + (16 + r16) * 16]);
                    acc0 = __builtin_amdgcn_mfma_f32_16x16x32_bf16(ahf[ks], b0, acc0, 0, 0, 0);
                    acc1 = __builtin_amdgcn_mfma_f32_16x16x32_bf16(ahf[ks], b1, acc1, 0, 0, 0);
                }
            } else {
                wait_two_fence(cnt, (unsigned)(LBLK * (t + 1)), (unsigned)(LBLK * t), tid, lane);
                const bf16_t* ax = h0buf + (size_t)(t & mask0) * BH + arow_off;
                const bf16_t* ah = h1buf + (size_t)((t - 1) & mask1) * BH + arow_off;
                bf16x8 axf[16], ahf[16];
                #pragma unroll
                for (int ks = 0; ks < 16; ++ks)
                    axf[ks] = *reinterpret_cast<const bf16x8*>(ax + ks * 32);
                #pragma unroll
                for (int ks = 0; ks < 16; ++ks)
                    ahf[ks] = *reinterpret_cast<const bf16x8*>(ah + ks * 32);
                #pragma unroll
                for (int ks = 0; ks < 16; ++ks) {
                    int gr = kh * 64 + ks * 4 + quad;
                    bf16x8 b0 = *reinterpret_cast<const bf16x8*>(&lds_w[gr * 512 + r16 * 16]);
                    bf16x8 b1 = *reinterpret_cast<const bf16x8*>(&lds_w[gr * 512 + (16 + r16) * 16]);
                    acc0 = __builtin_amdgcn_mfma_f32_16x16x32_bf16(axf[ks], b0, acc0, 0, 0, 0);
                    acc1 = __builtin_amdgcn_mfma_f32_16x16x32_bf16(axf[ks], b1, acc1, 0, 0, 0);
                }
                #pragma unroll
                for (int ks = 0; ks < 16; ++ks) {
                    int gr = 128 + kh * 64 + ks * 4 + quad;
                    bf16x8 b0 = *reinterpret_cast<const bf16x8*>(&lds_w[gr * 512 + r16 * 16]);
                    bf16x8 b1 = *reinterpret_cast<const bf16x8*>(&lds_w[gr * 512 + (16 + r16) * 16]);
                    acc0 = __builtin_amdgcn_mfma_f32_16x16x32_bf16(ahf[ks], b0, acc0, 0, 0, 0);
                    acc1 = __builtin_amdgcn_mfma_f32_16x16x32_bf16(ahf[ks], b1, acc1, 0, 0, 0);
                }
            }
        }

        // ---- K-half reduce: wave (mt,kh) keeps N-tile kh, ships the other ----
        {
            f32x4 ship = kh ? acc0 : acc1;
            *reinterpret_cast<f32x4*>(&lds_red[wv * 256 + lane * 4]) = ship;
            __syncthreads();
            f32x4 part = *reinterpret_cast<const f32x4*>(&lds_red[(wv ^ 1) * 256 + lane * 4]);
            f32x4 keep = kh ? acc1 : acc0;
            acc0 = keep + part;
        }

        // ---- gather 4 gates for (b_loc, uu); C layout: col=lane&15, row=quad*4+reg ----
        {
            const int quad_s = b_loc >> 2;
            const int reg_s  = b_loc & 3;
            float gsum[4];
            #pragma unroll
            for (int gi = 0; gi < 4; ++gi) {
                int lane_s = (quad_s << 4) | (4 * uu + gi);
                float v0 = __shfl(acc0[0], lane_s, 64);
                float v1 = __shfl(acc0[1], lane_s, 64);
                float v2 = __shfl(acc0[2], lane_s, 64);
                float v3 = __shfl(acc0[3], lane_s, 64);
                float v  = (reg_s == 0) ? v0 : (reg_s == 1) ? v1 : (reg_s == 2) ? v2 : v3;
                gsum[gi] = v + bias_r[gi];
            }
            float fg = sigmoid_f(gsum[0]);
            float ig = sigmoid_f(gsum[1]);
            float og = sigmoid_f(gsum[2]);
            float cx = tanh_f(gsum[3]);
            float cN = fg * c_reg + ig * cx;
            float h  = og * tanh_f(cN);
            c_reg = cN;
            lds_hf[b_glob * 8 + u_loc] = h;
            if (t == S_LEN - 1) {
                hfin[(size_t)l * BH + (size_t)b_glob * HID + u_glob] = h;
                cfin[(size_t)l * BH + (size_t)b_glob * HID + u_glob] = cN;
            }
        }
        __syncthreads();

        // ---- publish: wave 0 stores 64 batches x 8 units, write-through to LLC ----
        if (tid < 64) {
            const float* hp = &lds_hf[lane * 8];
            union { bf16x4 v; u64 q; } p0, p1;
            #pragma unroll
            for (int j = 0; j < 4; ++j) {
                p0.v[j] = (bf16_t)hp[j];
                p1.v[j] = (bf16_t)hp[4 + j];
            }
            bf16_t* dst = pubbuf + (size_t)(t & pubmask) * BH + (size_t)lane * HID + 8 * ug8;
            __hip_atomic_store((u64*)(void*)dst,       p0.q, __ATOMIC_RELAXED, __HIP_MEMORY_SCOPE_AGENT);
            __hip_atomic_store((u64*)(void*)(dst + 4), p1.q, __ATOMIC_RELAXED, __HIP_MEMORY_SCOPE_AGENT);
            asm volatile("s_waitcnt vmcnt(0)" ::: "memory");  // data at LLC before progress tick
            if (lane == 0) atomicAdd(mycnt, 1u);
            if (l == 1) {   // fp32 output, off the sync critical path
                float* yd = ys + (size_t)t * BH + (size_t)lane * HID + 8 * ug8;
                __builtin_nontemporal_store(*reinterpret_cast<const f32x4*>(hp),     reinterpret_cast<f32x4*>(yd));
                __builtin_nontemporal_store(*reinterpret_cast<const f32x4*>(hp + 4), reinterpret_cast<f32x4*>(yd + 4));
            }
        }

        // L0: prefetch next step's x fragments (latency hides under next wait)
        if (l == 0 && t + 1 < S_LEN) {
            const float* arow = x + (size_t)(t + 1) * BH + arow_off;
            #pragma unroll
            for (int ks = 0; ks < 16; ++ks) axp[ks] = cvt8(arow + ks * 32);
        }
    }
}

extern "C" void kernel_launch(void* const* d_in, const int* in_sizes, int n_in,
                              void* d_out, int out_size, void* d_ws, size_t ws_size,
                              hipStream_t stream) {
    (void)in_sizes; (void)n_in; (void)out_size;
    const float* x  = (const float*)d_in[0];
    const float* h0 = (const float*)d_in[1];
    const float* c0 = (const float*)d_in[2];
    const float* Wx = (const float*)d_in[3];
    const float* Wh = (const float*)d_in[4];
    const float* bx = (const float*)d_in[5];
    const float* bh = (const float*)d_in[6];

    unsigned char* ws = (unsigned char*)d_ws;
    unsigned* cnt = (unsigned*)ws;                       // 32 counters, 128 B apart
    size_t off = 32768;
    size_t need_ff = off + (size_t)2 * S_LEN * BH * 2;   // two 64 MB h-buffers
    int ff, mask0, mask1;
    bf16_t *h0buf, *h1buf;
    if (ws_size >= need_ff) {
        ff = 1; mask0 = S_LEN - 1; mask1 = S_LEN - 1;    // per-step-unique slots
        h0buf = (bf16_t*)(ws + off); off += (size_t)S_LEN * BH * 2;
        h1buf = (bf16_t*)(ws + off);
    } else {
        ff = 0; mask0 = 7; mask1 = 1;                    // ring + fence fallback
        h0buf = (bf16_t*)(ws + off); off += (size_t)8 * BH * 2;
        h1buf = (bf16_t*)(ws + off);
    }

    prep_kernel<<<2048, 256, 0, stream>>>(h0, h0buf, h1buf, cnt, mask0, mask1);
    lstm_persistent<<<NBLK, NTHR, 0, stream>>>(x, c0, Wx, Wh, bx, bh, (float*)d_out,
                                               h0buf, h1buf, cnt, ff, mask0, mask1);
}

// Round 4
// 6419.024 us; speedup vs baseline: 2.7632x; 1.0377x over previous
//
#include <hip/hip_runtime.h>

typedef __bf16 bf16_t;
typedef __bf16 bf16x8 __attribute__((ext_vector_type(8)));
typedef __bf16 bf16x4 __attribute__((ext_vector_type(4)));
typedef float  f32x4  __attribute__((ext_vector_type(4)));
typedef unsigned long long u64;

#define S_LEN 512
#define BATCH 64
#define HID 1024
#define BH (BATCH*HID)          /* 65536 */
#define G4 (4*HID)
#define NBLK 256                /* 128 layer-0 + 128 layer-1, 1 block/CU */
#define LBLK 128                /* blocks per layer */
#define NTHR 512                /* 8 waves: 4 M-tiles x 2 K-halves */
#define CSTRIDE 32              /* counter spacing: 128 B */
#define NCHK 8                  /* chunk counters per layer; chunk = 16 blocks = 128 K */

__device__ __forceinline__ float sigmoid_f(float x) { return 1.f / (1.f + __expf(-x)); }
__device__ __forceinline__ float tanh_f(float x) {
    float e = __expf(-2.f * fabsf(x));
    float t = (1.f - e) / (1.f + e);
    return x >= 0.f ? t : -t;
}

__device__ __forceinline__ bf16x8 cvt8(const float* p) {
    float4 a = *reinterpret_cast<const float4*>(p);
    float4 b = *reinterpret_cast<const float4*>(p + 4);
    bf16x8 r;
    r[0] = (bf16_t)a.x; r[1] = (bf16_t)a.y; r[2] = (bf16_t)a.z; r[3] = (bf16_t)a.w;
    r[4] = (bf16_t)b.x; r[5] = (bf16_t)b.y; r[6] = (bf16_t)b.z; r[7] = (bf16_t)b.w;
    return r;
}

// Per-wave spin on ONE chunk counter (uniform address, coalesced to 1 request).
// Memory clobber stops the compiler from hoisting subsequent data loads above the poll.
__device__ __forceinline__ void wait_chunk(const unsigned* cp, unsigned thr) {
    if (__hip_atomic_load(cp, __ATOMIC_RELAXED, __HIP_MEMORY_SCOPE_AGENT) < thr) {
        do { __builtin_amdgcn_s_sleep(2); }
        while (__hip_atomic_load(cp, __ATOMIC_RELAXED, __HIP_MEMORY_SCOPE_AGENT) < thr);
    }
    asm volatile("" ::: "memory");
}

// Chunk-streamed half-GEMM (one operand phase, K=512 for this wave's K-half).
// Chunks of 128 K gated by producer chunk-counters; 1-deep load pipeline.
__device__ __forceinline__ void gemm_phase_chunked(
    const bf16_t* __restrict__ abase, const unsigned* __restrict__ cbase, unsigned thr,
    int grbase, const unsigned char* __restrict__ lds_w,
    int kh, int quad, int r16, int ff, f32x4& acc0, f32x4& acc1)
{
    bf16x8 af[8];
    wait_chunk(&cbase[(4 * kh) * CSTRIDE], thr);
    if (!ff) __builtin_amdgcn_fence(__ATOMIC_ACQUIRE, "agent");   // ring fallback only
    #pragma unroll
    for (int j = 0; j < 4; ++j)
        af[j] = *reinterpret_cast<const bf16x8*>(abase + j * 32);
    #pragma unroll
    for (int c = 0; c < 4; ++c) {
        if (c < 3) {
            wait_chunk(&cbase[(4 * kh + c + 1) * CSTRIDE], thr);
            if (!ff) __builtin_amdgcn_fence(__ATOMIC_ACQUIRE, "agent");
            #pragma unroll
            for (int j = 0; j < 4; ++j)
                af[((c + 1) & 1) * 4 + j] =
                    *reinterpret_cast<const bf16x8*>(abase + (4 * (c + 1) + j) * 32);
        }
        #pragma unroll
        for (int j = 0; j < 4; ++j) {
            int ks = 4 * c + j;
            int gr = grbase + kh * 64 + ks * 4 + quad;
            bf16x8 b0 = *reinterpret_cast<const bf16x8*>(&lds_w[gr * 512 + r16 * 16]);
            bf16x8 b1 = *reinterpret_cast<const bf16x8*>(&lds_w[gr * 512 + (16 + r16) * 16]);
            acc0 = __builtin_amdgcn_mfma_f32_16x16x32_bf16(af[(c & 1) * 4 + j], b0, acc0, 0, 0, 0);
            acc1 = __builtin_amdgcn_mfma_f32_16x16x32_bf16(af[(c & 1) * 4 + j], b1, acc1, 0, 0, 0);
        }
    }
}

// prep: zero chunk counters, prefill bf16 h-buffers (t = -1 slot = mask).
__global__ void prep_kernel(const float* __restrict__ h0,
                            bf16_t* __restrict__ h0buf, bf16_t* __restrict__ h1buf,
                            unsigned* __restrict__ cnt, int mask0, int mask1) {
    int gtid = blockIdx.x * blockDim.x + threadIdx.x;
    int gsz  = gridDim.x * blockDim.x;
    if (gtid < 2 * NCHK) cnt[gtid * CSTRIDE] = 0u;
    for (int i = gtid; i < BH; i += gsz) {
        h0buf[(size_t)mask0 * BH + i] = (bf16_t)h0[i];
        h1buf[(size_t)mask1 * BH + i] = (bf16_t)h0[BH + i];
    }
}

// Persistent pipelined LSTM, producer-granular chunk dataflow.
// Block b: layer l=b>>7, unit-group ug8=b&127 (8 hidden units -> 32 gate rows).
// LDS weights: [256 granules][32 rows] bf16x8 = 128 KB (0-127 Wx, 128-255 Wh).
// Waves: wv = 2*mt + kh; mt = M-tile (16 batches), kh = K-half.
// Chunk counter (l, c) is ticked by the 16 blocks producing units [128c,128c+128);
// counter == 16*(u+1) <=> all of chunk c published step u. Each wave waits only
// the chunks of its own K-half, streaming loads+MFMAs as producers finish.
__global__ __launch_bounds__(NTHR, 2) void lstm_persistent(
    const float* __restrict__ x,
    const float* __restrict__ c0,
    const float* __restrict__ Wx,
    const float* __restrict__ Wh,
    const float* __restrict__ bx,
    const float* __restrict__ bh,
    float* __restrict__ out,
    bf16_t* __restrict__ h0buf,
    bf16_t* __restrict__ h1buf,
    unsigned* __restrict__ cnt,
    int ff, int mask0, int mask1)
{
    __shared__ __attribute__((aligned(16))) unsigned char lds_w[256 * 512];  // 128 KB
    __shared__ __attribute__((aligned(16))) float lds_red[8 * 256];          // 8 KB K-reduce
    __shared__ __attribute__((aligned(16))) float lds_hf[BATCH * 8];         // 2 KB h staging

    const int tid  = threadIdx.x;
    const int bid  = blockIdx.x;
    const int l    = bid >> 7;
    const int ug8  = bid & 127;
    const int lane = tid & 63;
    const int wv   = tid >> 6;
    const int mt   = wv >> 1;
    const int kh   = wv & 1;
    const int quad = lane >> 4;
    const int r16  = lane & 15;

    float* ys   = out;
    float* hfin = out + (size_t)S_LEN * BH;
    float* cfin = hfin + 2 * BH;

    // ---- stage this block's 32 weight rows (fp32 -> bf16) into LDS [gran][row] ----
    {
        const float* WxL = Wx + (size_t)l * G4 * HID;
        const float* WhL = Wh + (size_t)l * G4 * HID;
        for (int ch = tid; ch < 32 * 256; ch += NTHR) {
            int row = ch & 31;           // row = 4*unit_local + gate
            int gr  = ch >> 5;
            int ul = row >> 2, g = row & 3;
            size_t R = (size_t)g * HID + 8 * ug8 + ul;
            const float* src = (gr < 128) ? (WxL + R * HID + (size_t)gr * 8)
                                          : (WhL + R * HID + (size_t)(gr - 128) * 8);
            *reinterpret_cast<bf16x8*>(&lds_w[gr * 512 + row * 16]) = cvt8(src);
        }
    }

    const int b_loc  = lane >> 2;
    const int uu     = lane & 3;
    const int b_glob = 16 * mt + b_loc;
    const int u_loc  = 4 * kh + uu;
    const int u_glob = 8 * ug8 + u_loc;

    float bias_r[4];
    #pragma unroll
    for (int gi = 0; gi < 4; ++gi) {
        int R = gi * HID + u_glob;
        bias_r[gi] = bx[l * G4 + R] + bh[l * G4 + R];
    }
    float c_reg = c0[(size_t)l * BH + (size_t)b_glob * HID + u_glob];

    bf16_t* pubbuf = (l == 0) ? h0buf : h1buf;
    const int pubmask = (l == 0) ? mask0 : mask1;
    const unsigned* cnt0 = cnt;                         // layer-0 chunk counters
    const unsigned* cnt1 = cnt + NCHK * CSTRIDE;        // layer-1 chunk counters
    unsigned* mycnt = &cnt[(l * NCHK + (ug8 >> 4)) * CSTRIDE];
    __syncthreads();

    const int arow_off = (16 * mt + r16) * HID + kh * 512 + quad * 8;

    // L0: prefetch x fragments for t=0 into registers
    bf16x8 axp[16];
    if (l == 0) {
        const float* arow = x + arow_off;
        #pragma unroll
        for (int ks = 0; ks < 16; ++ks) axp[ks] = cvt8(arow + ks * 32);
    }

    for (int t = 0; t < S_LEN; ++t) {
        f32x4 acc0 = {0.f, 0.f, 0.f, 0.f};
        f32x4 acc1 = {0.f, 0.f, 0.f, 0.f};

        if (l == 0) {
            // ---- x-part from prefetched registers (no cross-block dependency) ----
            #pragma unroll
            for (int ks = 0; ks < 16; ++ks) {
                int gr = kh * 64 + ks * 4 + quad;
                bf16x8 b0 = *reinterpret_cast<const bf16x8*>(&lds_w[gr * 512 + r16 * 16]);
                bf16x8 b1 = *reinterpret_cast<const bf16x8*>(&lds_w[gr * 512 + (16 + r16) * 16]);
                acc0 = __builtin_amdgcn_mfma_f32_16x16x32_bf16(axp[ks], b0, acc0, 0, 0, 0);
                acc1 = __builtin_amdgcn_mfma_f32_16x16x32_bf16(axp[ks], b1, acc1, 0, 0, 0);
            }
            // ---- h-part: chunk-streamed from h0buf[t-1] (thr: chunk published t-1) ----
            const bf16_t* ah = h0buf + (size_t)((t - 1) & mask0) * BH + arow_off;
            gemm_phase_chunked(ah, cnt0, (unsigned)(16 * t), 128, lds_w,
                               kh, quad, r16, ff, acc0, acc1);
        } else {
            // ---- x-part: chunk-streamed from h0buf[t] (thr: L0 chunk published t) ----
            const bf16_t* ax = h0buf + (size_t)(t & mask0) * BH + arow_off;
            gemm_phase_chunked(ax, cnt0, (unsigned)(16 * (t + 1)), 0, lds_w,
                               kh, quad, r16, ff, acc0, acc1);
            // ---- h-part: chunk-streamed from h1buf[t-1] ----
            const bf16_t* ah = h1buf + (size_t)((t - 1) & mask1) * BH + arow_off;
            gemm_phase_chunked(ah, cnt1, (unsigned)(16 * t), 128, lds_w,
                               kh, quad, r16, ff, acc0, acc1);
        }

        // ---- K-half reduce: wave (mt,kh) keeps N-tile kh, ships the other ----
        {
            f32x4 ship = kh ? acc0 : acc1;
            *reinterpret_cast<f32x4*>(&lds_red[wv * 256 + lane * 4]) = ship;
            __syncthreads();
            f32x4 part = *reinterpret_cast<const f32x4*>(&lds_red[(wv ^ 1) * 256 + lane * 4]);
            f32x4 keep = kh ? acc1 : acc0;
            acc0 = keep + part;
        }

        // ---- gather 4 gates for (b_loc, uu); C layout: col=lane&15, row=quad*4+reg ----
        {
            const int quad_s = b_loc >> 2;
            const int reg_s  = b_loc & 3;
            float gsum[4];
            #pragma unroll
            for (int gi = 0; gi < 4; ++gi) {
                int lane_s = (quad_s << 4) | (4 * uu + gi);
                float v0 = __shfl(acc0[0], lane_s, 64);
                float v1 = __shfl(acc0[1], lane_s, 64);
                float v2 = __shfl(acc0[2], lane_s, 64);
                float v3 = __shfl(acc0[3], lane_s, 64);
                float v  = (reg_s == 0) ? v0 : (reg_s == 1) ? v1 : (reg_s == 2) ? v2 : v3;
                gsum[gi] = v + bias_r[gi];
            }
            float fg = sigmoid_f(gsum[0]);
            float ig = sigmoid_f(gsum[1]);
            float og = sigmoid_f(gsum[2]);
            float cx = tanh_f(gsum[3]);
            float cN = fg * c_reg + ig * cx;
            float h  = og * tanh_f(cN);
            c_reg = cN;
            lds_hf[b_glob * 8 + u_loc] = h;
            if (t == S_LEN - 1) {
                hfin[(size_t)l * BH + (size_t)b_glob * HID + u_glob] = h;
                cfin[(size_t)l * BH + (size_t)b_glob * HID + u_glob] = cN;
            }
        }
        __syncthreads();

        // ---- publish: wave 0 stores 64 batches x 8 units, write-through to LLC ----
        if (tid < 64) {
            // ring fallback: before overwriting slot t&7 (held h0[t-8]), make sure
            // every L1 block has consumed it (published >= t-7).
            if (!ff && l == 0 && t >= 8) {
                #pragma unroll
                for (int c = 0; c < NCHK; ++c)
                    wait_chunk(&cnt1[c * CSTRIDE], (unsigned)(16 * (t - 6)));
            }
            const float* hp = &lds_hf[lane * 8];
            union { bf16x4 v; u64 q; } p0, p1;
            #pragma unroll
            for (int j = 0; j < 4; ++j) {
                p0.v[j] = (bf16_t)hp[j];
                p1.v[j] = (bf16_t)hp[4 + j];
            }
            bf16_t* dst = pubbuf + (size_t)(t & pubmask) * BH + (size_t)lane * HID + 8 * ug8;
            __hip_atomic_store((u64*)(void*)dst,       p0.q, __ATOMIC_RELAXED, __HIP_MEMORY_SCOPE_AGENT);
            __hip_atomic_store((u64*)(void*)(dst + 4), p1.q, __ATOMIC_RELAXED, __HIP_MEMORY_SCOPE_AGENT);
            asm volatile("s_waitcnt vmcnt(0)" ::: "memory");  // data at LLC before tick
            if (lane == 0)
                __hip_atomic_fetch_add(mycnt, 1u, __ATOMIC_RELAXED, __HIP_MEMORY_SCOPE_AGENT);
            if (l == 1) {   // fp32 output, off the sync critical path
                float* yd = ys + (size_t)t * BH + (size_t)lane * HID + 8 * ug8;
                __builtin_nontemporal_store(*reinterpret_cast<const f32x4*>(hp),     reinterpret_cast<f32x4*>(yd));
                __builtin_nontemporal_store(*reinterpret_cast<const f32x4*>(hp + 4), reinterpret_cast<f32x4*>(yd + 4));
            }
        }

        // L0: prefetch next step's x fragments (latency hides under next wait)
        if (l == 0 && t + 1 < S_LEN) {
            const float* arow = x + (size_t)(t + 1) * BH + arow_off;
            #pragma unroll
            for (int ks = 0; ks < 16; ++ks) axp[ks] = cvt8(arow + ks * 32);
        }
    }
}

extern "C" void kernel_launch(void* const* d_in, const int* in_sizes, int n_in,
                              void* d_out, int out_size, void* d_ws, size_t ws_size,
                              hipStream_t stream) {
    (void)in_sizes; (void)n_in; (void)out_size;
    const float* x  = (const float*)d_in[0];
    const float* h0 = (const float*)d_in[1];
    const float* c0 = (const float*)d_in[2];
    const float* Wx = (const float*)d_in[3];
    const float* Wh = (const float*)d_in[4];
    const float* bx = (const float*)d_in[5];
    const float* bh = (const float*)d_in[6];

    unsigned char* ws = (unsigned char*)d_ws;
    unsigned* cnt = (unsigned*)ws;                       // 16 chunk counters, 128 B apart
    size_t off = 32768;
    size_t need_ff = off + (size_t)2 * S_LEN * BH * 2;   // two 64 MB h-buffers
    int ff, mask0, mask1;
    bf16_t *h0buf, *h1buf;
    if (ws_size >= need_ff) {
        ff = 1; mask0 = S_LEN - 1; mask1 = S_LEN - 1;    // per-step-unique slots
        h0buf = (bf16_t*)(ws + off); off += (size_t)S_LEN * BH * 2;
        h1buf = (bf16_t*)(ws + off);
    } else {
        ff = 0; mask0 = 7; mask1 = 1;                    // ring + fence fallback
        h0buf = (bf16_t*)(ws + off); off += (size_t)8 * BH * 2;
        h1buf = (bf16_t*)(ws + off);
    }

    prep_kernel<<<2048, 256, 0, stream>>>(h0, h0buf, h1buf, cnt, mask0, mask1);
    lstm_persistent<<<NBLK, NTHR, 0, stream>>>(x, c0, Wx, Wh, bx, bh, (float*)d_out,
                                               h0buf, h1buf, cnt, ff, mask0, mask1);
}